// Round 1
// baseline (522.419 us; speedup 1.0000x reference)
//
#include <hip/hip_runtime.h>
#include <stdint.h>
#include <stddef.h>

// Problem constants
#define NV    32000
#define HDIM  512
#define LSRC  320
#define MROWS 1024          // B * L_R
#define SCALEF 0.044194173824159216f   // 1/sqrt(512)

typedef unsigned short u16;
typedef unsigned int   u32;
typedef __attribute__((ext_vector_type(8))) short short8;   // 8 bf16 = 4 VGPRs (MFMA operand)
typedef __attribute__((ext_vector_type(4))) float floatx4;  // MFMA accumulator

// ---- helpers ----------------------------------------------------------------
__device__ __forceinline__ u16 f2bf(float f) {            // f32 -> bf16, RNE
  u32 x = __float_as_uint(f);
  return (u16)((x + 0x7fffu + ((x >> 16) & 1u)) >> 16);
}

__device__ __forceinline__ void async16(void* lds, const void* g) {
  // 16B-wide global -> LDS DMA. LDS dest must be wave-uniform; HW adds lane*16.
  __builtin_amdgcn_global_load_lds((const __attribute__((address_space(1))) u32*)g,
                                   (__attribute__((address_space(3))) u32*)lds,
                                   16, 0, 0);
}

// ---- K1: dec_out f32 -> bf16, tiled [mt(8)][kt(16)][mi(128)][ki(32)] --------
__global__ __launch_bounds__(256) void k_convA(const float* __restrict__ dec,
                                               u16* __restrict__ Ab) {
  int t = blockIdx.x * 256 + threadIdx.x;     // 65536 threads, 8 elems each
  int o = t * 8;
  int tile = o >> 12;                          // 4096 elems per tile
  int mt = tile >> 4, kt = tile & 15;
  int mi = (o & 4095) >> 5, ki = o & 31;       // ki in {0,8,16,24}
  const float* s = dec + (size_t)(mt * 128 + mi) * HDIM + kt * 32 + ki;
  float4 a = ((const float4*)s)[0];
  float4 b = ((const float4*)s)[1];
  union { u16 h[8]; uint4 v; } pk;
  pk.h[0] = f2bf(a.x); pk.h[1] = f2bf(a.y); pk.h[2] = f2bf(a.z); pk.h[3] = f2bf(a.w);
  pk.h[4] = f2bf(b.x); pk.h[5] = f2bf(b.y); pk.h[6] = f2bf(b.z); pk.h[7] = f2bf(b.w);
  *(uint4*)(Ab + o) = pk.v;
}

// ---- K2: W_gen f32 [k][n] -> bf16 tiled [nt(250)][kt(16)][ni(128)][ki(32)] --
// (transpose k<->n inner order via LDS; stride 36 breaks bank conflicts)
__global__ __launch_bounds__(256) void k_convW(const float* __restrict__ W,
                                               u16* __restrict__ Wb) {
  __shared__ u16 lds[128 * 36];
  int tileId = blockIdx.x;                 // 0..3999 = nt*16 + kt
  int nt = tileId >> 4, kt = tileId & 15;
  int t = threadIdx.x;
  const float* src = W + (size_t)kt * 32 * NV + (size_t)nt * 128;
#pragma unroll
  for (int i = 0; i < 16; ++i) {
    int e = t + 256 * i;                   // coalesced reads along n
    int kin = e >> 7, nin = e & 127;
    lds[nin * 36 + kin] = f2bf(src[(size_t)kin * NV + nin]);
  }
  __syncthreads();
  u16* dst = Wb + (size_t)tileId * 4096;
#pragma unroll
  for (int j = 0; j < 2; ++j) {
    int o = t * 8 + j * 2048;              // coalesced 16B writes
    int ni = o >> 5, ki0 = o & 31;
    const u16* p = &lds[ni * 36 + ki0];
    uint2 x = *(const uint2*)p;
    uint2 y = *(const uint2*)(p + 4);
    uint4 v; v.x = x.x; v.y = x.y; v.z = y.x; v.w = y.y;
    *(uint4*)(dst + o) = v;
  }
}

// ---- K3: copy-attention logits (fp32), exp, ws store, row-sum atomics -------
__global__ __launch_bounds__(256) void k_copy(const float* __restrict__ dec,
                                              const float* __restrict__ srch,
                                              const int* __restrict__ mask,
                                              float* __restrict__ wsCopy,
                                              float* __restrict__ rowSum) {
  __shared__ float dbuf[4 * HDIM];
  int blk = blockIdx.x;                    // 256 blocks = 8 b * 32 lgroups
  int b = blk >> 5, lg = blk & 31;         // 4 rows (l) per block
  int t = threadIdx.x;
  const float4* s4 = (const float4*)(dec + (size_t)(b * 128 + lg * 4) * HDIM);
  float4* d4 = (float4*)dbuf;
  d4[t] = s4[t];
  d4[t + 256] = s4[t + 256];
  __syncthreads();
  int l = t >> 6, sg = t & 63;             // one wave per output row
  int row = b * 128 + lg * 4 + l;
  const float4* dv = (const float4*)&dbuf[l * HDIM];
  float partial = 0.f;
#pragma unroll
  for (int so = 0; so < 5; ++so) {
    int s = so * 64 + sg;
    const float4* sv = (const float4*)(srch + ((size_t)b * LSRC + s) * HDIM);
    float a0 = 0.f, a1 = 0.f, a2 = 0.f, a3 = 0.f;
    for (int h = 0; h < 128; ++h) {
      float4 x = sv[h], y = dv[h];
      a0 += x.x * y.x; a1 += x.y * y.y; a2 += x.z * y.z; a3 += x.w * y.w;
    }
    float dot = (a0 + a1) + (a2 + a3);
    float e = mask[b * LSRC + s] ? __expf(dot * SCALEF) : 0.f;
    wsCopy[row * LSRC + s] = e;
    partial += e;
  }
  partial += __shfl_xor(partial, 1, 64);
  partial += __shfl_xor(partial, 2, 64);
  partial += __shfl_xor(partial, 4, 64);
  partial += __shfl_xor(partial, 8, 64);
  partial += __shfl_xor(partial, 16, 64);
  partial += __shfl_xor(partial, 32, 64);
  if (sg == 0) atomicAdd(&rowSum[row], partial);
}

// ---- K4: main GEMM 1024x32000x512 bf16 MFMA, epilogue exp -> bf16 ws --------
__global__ __launch_bounds__(256) void k_gemm(const u16* __restrict__ Ab,
                                              const u16* __restrict__ Wb,
                                              const float* __restrict__ bgen,
                                              u16* __restrict__ wsE,
                                              float* __restrict__ rowSum) {
  __shared__ u16 As[4096];   // [mi(128)][ki(32)]
  __shared__ u16 Bs[4096];   // [ni(128)][ki(32)]
  int t = threadIdx.x;
  int wid = t >> 6, lane = t & 63;
  int wm = wid >> 1, wn = wid & 1;         // 2x2 waves over 128x128 tile
  int quad = lane >> 4, l16 = lane & 15;
  const u16* Ag = Ab + (size_t)blockIdx.y * (16 * 4096);
  const u16* Bg = Wb + (size_t)blockIdx.x * (16 * 4096);
  floatx4 acc[4][4];
#pragma unroll
  for (int i = 0; i < 4; ++i)
#pragma unroll
    for (int j = 0; j < 4; ++j) acc[i][j] = (floatx4){0.f, 0.f, 0.f, 0.f};

  int cb1 = wid * 64, cb2 = wid * 64 + 256;  // 16B-chunk bases (wave-uniform)
  for (int kt = 0; kt < 16; ++kt) {
    const u16* at = Ag + kt * 4096;
    const u16* bt = Bg + kt * 4096;
    async16(&As[cb1 * 8], at + (size_t)(cb1 + lane) * 8);
    async16(&As[cb2 * 8], at + (size_t)(cb2 + lane) * 8);
    async16(&Bs[cb1 * 8], bt + (size_t)(cb1 + lane) * 8);
    async16(&Bs[cb2 * 8], bt + (size_t)(cb2 + lane) * 8);
    __syncthreads();                        // drains vmcnt for the DMA loads
    short8 af[4], bfr[4];
#pragma unroll
    for (int mt = 0; mt < 4; ++mt)
      af[mt] = *(const short8*)&As[(wm * 64 + mt * 16 + l16) * 32 + quad * 8];
#pragma unroll
    for (int nt = 0; nt < 4; ++nt)
      bfr[nt] = *(const short8*)&Bs[(wn * 64 + nt * 16 + l16) * 32 + quad * 8];
#pragma unroll
    for (int mt = 0; mt < 4; ++mt)
#pragma unroll
      for (int nt = 0; nt < 4; ++nt)
        acc[mt][nt] = __builtin_amdgcn_mfma_f32_16x16x32_bf16(af[mt], bfr[nt],
                                                              acc[mt][nt], 0, 0, 0);
    __syncthreads();
  }

  // epilogue: e = exp((acc + b) * H^-0.5); store bf16; reduce row sums
  int row0 = blockIdx.y * 128 + wm * 64;
  int col0 = blockIdx.x * 128 + wn * 64;
  float bg[4];
#pragma unroll
  for (int nt = 0; nt < 4; ++nt) bg[nt] = bgen[col0 + nt * 16 + l16];
#pragma unroll
  for (int mt = 0; mt < 4; ++mt) {
    float rs[4] = {0.f, 0.f, 0.f, 0.f};
#pragma unroll
    for (int nt = 0; nt < 4; ++nt) {
      int col = col0 + nt * 16 + l16;
#pragma unroll
      for (int r = 0; r < 4; ++r) {
        int row = row0 + mt * 16 + quad * 4 + r;    // C/D layout (m89)
        float e = __expf((acc[mt][nt][r] + bg[nt]) * SCALEF);
        wsE[(size_t)row * NV + col] = f2bf(e);
        rs[r] += e;
      }
    }
#pragma unroll
    for (int r = 0; r < 4; ++r) {
      float v = rs[r];
      v += __shfl_xor(v, 1, 64);
      v += __shfl_xor(v, 2, 64);
      v += __shfl_xor(v, 4, 64);
      v += __shfl_xor(v, 8, 64);
      if (l16 == 0) atomicAdd(&rowSum[row0 + mt * 16 + quad * 4 + r], v);
    }
  }
}

// ---- K5: normalize + scatter (one block owns one output row) ----------------
__global__ __launch_bounds__(256) void k_norm(const u16* __restrict__ wsE,
                                              const float* __restrict__ wsCopy,
                                              const float* __restrict__ rowSum,
                                              const int* __restrict__ context,
                                              const int* __restrict__ tp,
                                              const int* __restrict__ action,
                                              const int* __restrict__ loc2glo,
                                              float* __restrict__ out) {
  int r = blockIdx.x, b = r >> 7;
  float inv = 1.0f / rowSum[r];
  const uint4* src = (const uint4*)(wsE + (size_t)r * NV);
  float4* dst = (float4*)(out + (size_t)r * NV);
  for (int c = threadIdx.x; c < NV / 8; c += 256) {
    uint4 v = src[c];
    float4 lo, hi;
    lo.x = __uint_as_float(v.x << 16) * inv;
    lo.y = __uint_as_float(v.x & 0xffff0000u) * inv;
    lo.z = __uint_as_float(v.y << 16) * inv;
    lo.w = __uint_as_float(v.y & 0xffff0000u) * inv;
    hi.x = __uint_as_float(v.z << 16) * inv;
    hi.y = __uint_as_float(v.z & 0xffff0000u) * inv;
    hi.z = __uint_as_float(v.w << 16) * inv;
    hi.w = __uint_as_float(v.w & 0xffff0000u) * inv;
    dst[2 * c] = lo;
    dst[2 * c + 1] = hi;
  }
  __syncthreads();   // drains stores (vmcnt) so atomics below see them at L2
  int t = threadIdx.x;
  float* op = out + (size_t)r * NV;
  atomicAdd(op + context[b * 256 + t], wsCopy[r * LSRC + t] * inv);
  if (t < 32) {
    atomicAdd(op + loc2glo[tp[b * 32 + t]],     wsCopy[r * LSRC + 256 + t] * inv);
    atomicAdd(op + loc2glo[action[b * 32 + t]], wsCopy[r * LSRC + 288 + t] * inv);
  }
}

// ---- launch -----------------------------------------------------------------
extern "C" void kernel_launch(void* const* d_in, const int* in_sizes, int n_in,
                              void* d_out, int out_size, void* d_ws, size_t ws_size,
                              hipStream_t stream) {
  const float* dec  = (const float*)d_in[0];
  const float* srch = (const float*)d_in[1];
  const float* Wg   = (const float*)d_in[2];
  const float* bg   = (const float*)d_in[3];
  const int*   mask = (const int*)d_in[4];
  const int*   ctx  = (const int*)d_in[5];
  const int*   tp   = (const int*)d_in[6];
  const int*   act  = (const int*)d_in[7];
  const int*   l2g  = (const int*)d_in[8];
  float* out = (float*)d_out;

  char* ws = (char*)d_ws;
  // ws layout (bytes):
  u16*   Wb      = (u16*)(ws);                    // 32,768,000  bf16 W tiled
  u16*   wsE     = (u16*)(ws + 32768000);         // 65,536,000  bf16 exp(gen)
  u16*   Ab      = (u16*)(ws + 98304000);         //  1,048,576  bf16 A tiled
  float* wsCopy  = (float*)(ws + 99352576);       //  1,310,720  fp32 exp(copy)
  float* rowSum  = (float*)(ws + 100663296);      //      4,096  fp32 row sums

  hipMemsetAsync(rowSum, 0, MROWS * sizeof(float), stream);
  hipLaunchKernelGGL(k_convA, dim3(256), dim3(256), 0, stream, dec, Ab);
  hipLaunchKernelGGL(k_convW, dim3(4000), dim3(256), 0, stream, Wg, Wb);
  hipLaunchKernelGGL(k_copy, dim3(256), dim3(256), 0, stream, dec, srch, mask, wsCopy, rowSum);
  hipLaunchKernelGGL(k_gemm, dim3(250, 8), dim3(256), 0, stream, Ab, Wb, bg, wsE, rowSum);
  hipLaunchKernelGGL(k_norm, dim3(MROWS), dim3(256), 0, stream, wsE, wsCopy, rowSum,
                     ctx, tp, act, l2g, out);
}

// Round 2
// 416.923 us; speedup vs baseline: 1.2530x; 1.2530x over previous
//
#include <hip/hip_runtime.h>
#include <stdint.h>
#include <stddef.h>

// Problem constants
#define NV    32000
#define HDIM  512
#define LSRC  320
#define MROWS 1024          // B * L_R
#define SCALEF 0.044194173824159216f   // 1/sqrt(512)

typedef unsigned short u16;
typedef unsigned int   u32;
typedef __attribute__((ext_vector_type(8))) short short8;   // 8 bf16 = 4 VGPRs (MFMA operand)
typedef __attribute__((ext_vector_type(4))) float floatx4;  // MFMA accumulator

// ---- helpers ----------------------------------------------------------------
__device__ __forceinline__ u16 f2bf(float f) {            // f32 -> bf16, RNE
  u32 x = __float_as_uint(f);
  return (u16)((x + 0x7fffu + ((x >> 16) & 1u)) >> 16);
}

// ---- K1: dec_out f32 -> bf16, tiled [mt(8)][kt(16)][mi(128)][ki(32)] --------
__global__ __launch_bounds__(256) void k_convA(const float* __restrict__ dec,
                                               u16* __restrict__ Ab) {
  int t = blockIdx.x * 256 + threadIdx.x;     // 65536 threads, 8 elems each
  int o = t * 8;
  int tile = o >> 12;                          // 4096 elems per tile
  int mt = tile >> 4, kt = tile & 15;
  int mi = (o & 4095) >> 5, ki = o & 31;       // ki in {0,8,16,24}
  const float* s = dec + (size_t)(mt * 128 + mi) * HDIM + kt * 32 + ki;
  float4 a = ((const float4*)s)[0];
  float4 b = ((const float4*)s)[1];
  union { u16 h[8]; uint4 v; } pk;
  pk.h[0] = f2bf(a.x); pk.h[1] = f2bf(a.y); pk.h[2] = f2bf(a.z); pk.h[3] = f2bf(a.w);
  pk.h[4] = f2bf(b.x); pk.h[5] = f2bf(b.y); pk.h[6] = f2bf(b.z); pk.h[7] = f2bf(b.w);
  *(uint4*)(Ab + o) = pk.v;
}

// ---- K2: W_gen f32 [k][n] -> bf16 tiled [nt(250)][kt(16)][ni(128)][ki(32)] --
// (transpose k<->n inner order via LDS; stride 36 breaks bank conflicts)
__global__ __launch_bounds__(256) void k_convW(const float* __restrict__ W,
                                               u16* __restrict__ Wb) {
  __shared__ u16 lds[128 * 36];
  int tileId = blockIdx.x;                 // 0..3999 = nt*16 + kt
  int nt = tileId >> 4, kt = tileId & 15;
  int t = threadIdx.x;
  const float* src = W + (size_t)kt * 32 * NV + (size_t)nt * 128;
#pragma unroll
  for (int i = 0; i < 4; ++i) {
    int f = t + 256 * i;                   // float4 id, 0..1023
    int kin = f >> 5, n4 = f & 31;         // coalesced float4 reads along n
    float4 v = *(const float4*)(src + (size_t)kin * NV + n4 * 4);
    int base = (n4 * 4) * 36 + kin;
    lds[base]       = f2bf(v.x);
    lds[base + 36]  = f2bf(v.y);
    lds[base + 72]  = f2bf(v.z);
    lds[base + 108] = f2bf(v.w);
  }
  __syncthreads();
  u16* dst = Wb + (size_t)tileId * 4096;
#pragma unroll
  for (int j = 0; j < 2; ++j) {
    int o = t * 8 + j * 2048;              // coalesced 16B writes
    int ni = o >> 5, ki0 = o & 31;
    const u16* p = &lds[ni * 36 + ki0];
    uint2 x = *(const uint2*)p;
    uint2 y = *(const uint2*)(p + 4);
    uint4 v; v.x = x.x; v.y = x.y; v.z = y.x; v.w = y.y;
    *(uint4*)(dst + o) = v;
  }
}

// ---- K3: copy-attention logits (fp32), coalesced h-lanes + shuffle reduce ---
// grid = B * 40 blocks; each block: 8 s-rows x 128 l-rows; wave owns 2 s-rows.
__global__ __launch_bounds__(256) void k_copy(const float* __restrict__ dec,
                                              const float* __restrict__ srch,
                                              const int* __restrict__ mask,
                                              float* __restrict__ wsCopy,
                                              float* __restrict__ rowSum) {
  __shared__ float rowAcc[128];
  int blk = blockIdx.x;                    // 320 = b*40 + st
  int b = blk / 40, st = blk % 40;
  int s0 = st * 8;
  int t = threadIdx.x;
  if (t < 128) rowAcc[t] = 0.f;
  int w = t >> 6, lane = t & 63;
  int sA = s0 + 2 * w, sB = sA + 1;
  int mA = mask[b * LSRC + sA], mB = mask[b * LSRC + sB];
  // hoist the two srch rows into registers (coalesced float4 loads)
  const float4* a4 = (const float4*)(srch + ((size_t)b * LSRC + sA) * HDIM);
  const float4* b4 = (const float4*)(srch + ((size_t)b * LSRC + sB) * HDIM);
  float4 av0 = a4[lane], av1 = a4[lane + 64];
  float4 bv0 = b4[lane], bv1 = b4[lane + 64];
  __syncthreads();
  for (int l = 0; l < 128; ++l) {
    const float4* dp = (const float4*)(dec + ((size_t)b * 128 + l) * HDIM);
    float4 d0 = dp[lane], d1 = dp[lane + 64];
    float pa = d0.x * av0.x + d0.y * av0.y + d0.z * av0.z + d0.w * av0.w
             + d1.x * av1.x + d1.y * av1.y + d1.z * av1.z + d1.w * av1.w;
    float pb = d0.x * bv0.x + d0.y * bv0.y + d0.z * bv0.z + d0.w * bv0.w
             + d1.x * bv1.x + d1.y * bv1.y + d1.z * bv1.z + d1.w * bv1.w;
#pragma unroll
    for (int sh = 1; sh < 64; sh <<= 1) {
      pa += __shfl_xor(pa, sh, 64);
      pb += __shfl_xor(pb, sh, 64);
    }
    if (lane == 0) {
      float eA = mA ? __expf(pa * SCALEF) : 0.f;
      float eB = mB ? __expf(pb * SCALEF) : 0.f;
      int row = b * 128 + l;
      wsCopy[row * LSRC + sA] = eA;
      wsCopy[row * LSRC + sB] = eB;
      atomicAdd(&rowAcc[l], eA + eB);
    }
  }
  __syncthreads();
  if (t < 128) atomicAdd(&rowSum[b * 128 + t], rowAcc[t]);
}

// ---- K4: main GEMM 1024x32000x512 bf16 MFMA, register-direct (no LDS) -------
// grid (8, 250): x = m-tile, y = n-tile; consecutive blocks share the B tile.
__global__ __launch_bounds__(256, 3) void k_gemm(const u16* __restrict__ Ab,
                                                 const u16* __restrict__ Wb,
                                                 const float* __restrict__ bgen,
                                                 u16* __restrict__ wsE,
                                                 float* __restrict__ rowSum) {
  int t = threadIdx.x;
  int wid = t >> 6, lane = t & 63;
  int wm = wid >> 1, wn = wid & 1;         // 2x2 waves over 128x128 tile
  int quad = lane >> 4, l16 = lane & 15;
  const u16* Ag = Ab + (size_t)blockIdx.x * (16 * 4096)
                + (wm * 64 + l16) * 32 + quad * 8;
  const u16* Bg = Wb + (size_t)blockIdx.y * (16 * 4096)
                + (wn * 64 + l16) * 32 + quad * 8;
  floatx4 acc[4][4];
#pragma unroll
  for (int i = 0; i < 4; ++i)
#pragma unroll
    for (int j = 0; j < 4; ++j) acc[i][j] = (floatx4){0.f, 0.f, 0.f, 0.f};

  short8 aF[2][4], bF[2][4];
#pragma unroll
  for (int i = 0; i < 4; ++i) {            // prologue: kt=0 fragments
    aF[0][i] = *(const short8*)(Ag + i * 512);   // 16 rows * 32 k = 512 elems
    bF[0][i] = *(const short8*)(Bg + i * 512);
  }
#pragma unroll 2
  for (int kt = 0; kt < 16; ++kt) {
    int cur = kt & 1, nxt = cur ^ 1;
    if (kt < 15) {
      const u16* ap = Ag + (kt + 1) * 4096;
      const u16* bp = Bg + (kt + 1) * 4096;
#pragma unroll
      for (int i = 0; i < 4; ++i) {
        aF[nxt][i] = *(const short8*)(ap + i * 512);
        bF[nxt][i] = *(const short8*)(bp + i * 512);
      }
    }
#pragma unroll
    for (int mt = 0; mt < 4; ++mt)
#pragma unroll
      for (int nt = 0; nt < 4; ++nt)
        acc[mt][nt] = __builtin_amdgcn_mfma_f32_16x16x32_bf16(aF[cur][mt], bF[cur][nt],
                                                              acc[mt][nt], 0, 0, 0);
  }

  // epilogue: e = exp((acc + b) * H^-0.5); store bf16; reduce row sums
  int row0 = blockIdx.x * 128 + wm * 64;
  int col0 = blockIdx.y * 128 + wn * 64;
  float bg[4];
#pragma unroll
  for (int nt = 0; nt < 4; ++nt) bg[nt] = bgen[col0 + nt * 16 + l16];
#pragma unroll
  for (int mt = 0; mt < 4; ++mt) {
    float rs[4] = {0.f, 0.f, 0.f, 0.f};
#pragma unroll
    for (int nt = 0; nt < 4; ++nt) {
      int col = col0 + nt * 16 + l16;
#pragma unroll
      for (int r = 0; r < 4; ++r) {
        int row = row0 + mt * 16 + quad * 4 + r;    // C/D layout (m89)
        float e = __expf((acc[mt][nt][r] + bg[nt]) * SCALEF);
        wsE[(size_t)row * NV + col] = f2bf(e);
        rs[r] += e;
      }
    }
#pragma unroll
    for (int r = 0; r < 4; ++r) {
      float v = rs[r];
      v += __shfl_xor(v, 1, 64);
      v += __shfl_xor(v, 2, 64);
      v += __shfl_xor(v, 4, 64);
      v += __shfl_xor(v, 8, 64);
      if (l16 == 0) atomicAdd(&rowSum[row0 + mt * 16 + quad * 4 + r], v);
    }
  }
}

// ---- K5: normalize + scatter (one block owns one output row) ----------------
__global__ __launch_bounds__(256) void k_norm(const u16* __restrict__ wsE,
                                              const float* __restrict__ wsCopy,
                                              const float* __restrict__ rowSum,
                                              const int* __restrict__ context,
                                              const int* __restrict__ tp,
                                              const int* __restrict__ action,
                                              const int* __restrict__ loc2glo,
                                              float* __restrict__ out) {
  int r = blockIdx.x, b = r >> 7;
  float inv = 1.0f / rowSum[r];
  const uint4* src = (const uint4*)(wsE + (size_t)r * NV);
  float4* dst = (float4*)(out + (size_t)r * NV);
  for (int c = threadIdx.x; c < NV / 8; c += 256) {
    uint4 v = src[c];
    float4 lo, hi;
    lo.x = __uint_as_float(v.x << 16) * inv;
    lo.y = __uint_as_float(v.x & 0xffff0000u) * inv;
    lo.z = __uint_as_float(v.y << 16) * inv;
    lo.w = __uint_as_float(v.y & 0xffff0000u) * inv;
    hi.x = __uint_as_float(v.z << 16) * inv;
    hi.y = __uint_as_float(v.z & 0xffff0000u) * inv;
    hi.z = __uint_as_float(v.w << 16) * inv;
    hi.w = __uint_as_float(v.w & 0xffff0000u) * inv;
    dst[2 * c] = lo;
    dst[2 * c + 1] = hi;
  }
  __syncthreads();   // drains stores (vmcnt) so atomics below see them at L2
  int t = threadIdx.x;
  float* op = out + (size_t)r * NV;
  atomicAdd(op + context[b * 256 + t], wsCopy[r * LSRC + t] * inv);
  if (t < 32) {
    atomicAdd(op + loc2glo[tp[b * 32 + t]],     wsCopy[r * LSRC + 256 + t] * inv);
    atomicAdd(op + loc2glo[action[b * 32 + t]], wsCopy[r * LSRC + 288 + t] * inv);
  }
}

// ---- launch -----------------------------------------------------------------
extern "C" void kernel_launch(void* const* d_in, const int* in_sizes, int n_in,
                              void* d_out, int out_size, void* d_ws, size_t ws_size,
                              hipStream_t stream) {
  const float* dec  = (const float*)d_in[0];
  const float* srch = (const float*)d_in[1];
  const float* Wg   = (const float*)d_in[2];
  const float* bg   = (const float*)d_in[3];
  const int*   mask = (const int*)d_in[4];
  const int*   ctx  = (const int*)d_in[5];
  const int*   tp   = (const int*)d_in[6];
  const int*   act  = (const int*)d_in[7];
  const int*   l2g  = (const int*)d_in[8];
  float* out = (float*)d_out;

  char* ws = (char*)d_ws;
  // ws layout (bytes):
  u16*   Wb      = (u16*)(ws);                    // 32,768,000  bf16 W tiled
  u16*   wsE     = (u16*)(ws + 32768000);         // 65,536,000  bf16 exp(gen)
  u16*   Ab      = (u16*)(ws + 98304000);         //  1,048,576  bf16 A tiled
  float* wsCopy  = (float*)(ws + 99352576);       //  1,310,720  fp32 exp(copy)
  float* rowSum  = (float*)(ws + 100663296);      //      4,096  fp32 row sums

  hipMemsetAsync(rowSum, 0, MROWS * sizeof(float), stream);
  hipLaunchKernelGGL(k_convA, dim3(256), dim3(256), 0, stream, dec, Ab);
  hipLaunchKernelGGL(k_convW, dim3(4000), dim3(256), 0, stream, Wg, Wb);
  hipLaunchKernelGGL(k_copy, dim3(320), dim3(256), 0, stream, dec, srch, mask, wsCopy, rowSum);
  hipLaunchKernelGGL(k_gemm, dim3(8, 250), dim3(256), 0, stream, Ab, Wb, bg, wsE, rowSum);
  hipLaunchKernelGGL(k_norm, dim3(MROWS), dim3(256), 0, stream, wsE, wsCopy, rowSum,
                     ctx, tp, act, l2g, out);
}

// Round 3
// 363.153 us; speedup vs baseline: 1.4386x; 1.1481x over previous
//
#include <hip/hip_runtime.h>
#include <stdint.h>
#include <stddef.h>

// Problem constants
#define NV    32000
#define HDIM  512
#define LSRC  320
#define MROWS 1024          // B * L_R
#define SCALEF 0.044194173824159216f   // 1/sqrt(512)

typedef unsigned short u16;
typedef unsigned int   u32;
typedef __attribute__((ext_vector_type(8))) short short8;   // 8 bf16 = 4 VGPRs (MFMA operand)
typedef __attribute__((ext_vector_type(4))) float floatx4;  // MFMA accumulator

// ---- helpers ----------------------------------------------------------------
__device__ __forceinline__ u16 f2bf(float f) {            // f32 -> bf16, RNE
  u32 x = __float_as_uint(f);
  return (u16)((x + 0x7fffu + ((x >> 16) & 1u)) >> 16);
}

// ---- K1: dec_out f32 -> bf16, tiled [mt(8)][kt(16)][mi(128)][ki(32)] --------
// Also zeroes rowSum (block 0) so no separate memset dispatch is needed.
__global__ __launch_bounds__(256) void k_convA(const float* __restrict__ dec,
                                               u16* __restrict__ Ab,
                                               float* __restrict__ rowSum) {
  if (blockIdx.x == 0) {
    ((float4*)rowSum)[threadIdx.x] = (float4){0.f, 0.f, 0.f, 0.f};  // 1024 floats
  }
  int t = blockIdx.x * 256 + threadIdx.x;     // 65536 threads, 8 elems each
  int o = t * 8;
  int tile = o >> 12;                          // 4096 elems per tile
  int mt = tile >> 4, kt = tile & 15;
  int mi = (o & 4095) >> 5, ki = o & 31;       // ki in {0,8,16,24}
  const float* s = dec + (size_t)(mt * 128 + mi) * HDIM + kt * 32 + ki;
  float4 a = ((const float4*)s)[0];
  float4 b = ((const float4*)s)[1];
  union { u16 h[8]; uint4 v; } pk;
  pk.h[0] = f2bf(a.x); pk.h[1] = f2bf(a.y); pk.h[2] = f2bf(a.z); pk.h[3] = f2bf(a.w);
  pk.h[4] = f2bf(b.x); pk.h[5] = f2bf(b.y); pk.h[6] = f2bf(b.z); pk.h[7] = f2bf(b.w);
  *(uint4*)(Ab + o) = pk.v;
}

// ---- K2: W_gen f32 [k][n] -> bf16 tiled [nt(250)][kt(16)][ni(128)][ki(32)] --
// (transpose k<->n inner order via LDS; stride 36 breaks bank conflicts)
__global__ __launch_bounds__(256) void k_convW(const float* __restrict__ W,
                                               u16* __restrict__ Wb) {
  __shared__ u16 lds[128 * 36];
  int tileId = blockIdx.x;                 // 0..3999 = nt*16 + kt
  int nt = tileId >> 4, kt = tileId & 15;
  int t = threadIdx.x;
  const float* src = W + (size_t)kt * 32 * NV + (size_t)nt * 128;
#pragma unroll
  for (int i = 0; i < 4; ++i) {
    int f = t + 256 * i;                   // float4 id, 0..1023
    int kin = f >> 5, n4 = f & 31;         // coalesced float4 reads along n
    float4 v = *(const float4*)(src + (size_t)kin * NV + n4 * 4);
    int base = (n4 * 4) * 36 + kin;
    lds[base]       = f2bf(v.x);
    lds[base + 36]  = f2bf(v.y);
    lds[base + 72]  = f2bf(v.z);
    lds[base + 108] = f2bf(v.w);
  }
  __syncthreads();
  u16* dst = Wb + (size_t)tileId * 4096;
#pragma unroll
  for (int j = 0; j < 2; ++j) {
    int o = t * 8 + j * 2048;              // coalesced 16B writes
    int ni = o >> 5, ki0 = o & 31;
    const u16* p = &lds[ni * 36 + ki0];
    uint2 x = *(const uint2*)p;
    uint2 y = *(const uint2*)(p + 4);
    uint4 v; v.x = x.x; v.y = x.y; v.z = y.x; v.w = y.y;
    *(uint4*)(dst + o) = v;
  }
}

// ---- K3: copy-attention logits (fp32); grid = 8b x 40st x 4lq ---------------
// Each block: 8 s-rows x 32 l-rows; wave owns 2 s-rows. 4-way l-split for TLP.
__global__ __launch_bounds__(256) void k_copy(const float* __restrict__ dec,
                                              const float* __restrict__ srch,
                                              const int* __restrict__ mask,
                                              float* __restrict__ wsCopy,
                                              float* __restrict__ rowSum) {
  __shared__ float rowAcc[32];
  int blk = blockIdx.x;                    // 1280 = b*160 + st*4 + lq
  int b = blk / 160, r = blk % 160;
  int st = r >> 2, lq = r & 3;
  int s0 = st * 8, l0 = lq * 32;
  int t = threadIdx.x;
  if (t < 32) rowAcc[t] = 0.f;
  int w = t >> 6, lane = t & 63;
  int sA = s0 + 2 * w, sB = sA + 1;
  int mA = mask[b * LSRC + sA], mB = mask[b * LSRC + sB];
  // hoist the two srch rows into registers (coalesced float4 loads)
  const float4* a4 = (const float4*)(srch + ((size_t)b * LSRC + sA) * HDIM);
  const float4* b4 = (const float4*)(srch + ((size_t)b * LSRC + sB) * HDIM);
  float4 av0 = a4[lane], av1 = a4[lane + 64];
  float4 bv0 = b4[lane], bv1 = b4[lane + 64];
  __syncthreads();
  for (int li = 0; li < 32; ++li) {
    int l = l0 + li;
    const float4* dp = (const float4*)(dec + ((size_t)b * 128 + l) * HDIM);
    float4 d0 = dp[lane], d1 = dp[lane + 64];
    float pa = d0.x * av0.x + d0.y * av0.y + d0.z * av0.z + d0.w * av0.w
             + d1.x * av1.x + d1.y * av1.y + d1.z * av1.z + d1.w * av1.w;
    float pb = d0.x * bv0.x + d0.y * bv0.y + d0.z * bv0.z + d0.w * bv0.w
             + d1.x * bv1.x + d1.y * bv1.y + d1.z * bv1.z + d1.w * bv1.w;
#pragma unroll
    for (int sh = 1; sh < 64; sh <<= 1) {
      pa += __shfl_xor(pa, sh, 64);
      pb += __shfl_xor(pb, sh, 64);
    }
    if (lane == 0) {
      float eA = mA ? __expf(pa * SCALEF) : 0.f;
      float eB = mB ? __expf(pb * SCALEF) : 0.f;
      int row = b * 128 + l;
      wsCopy[row * LSRC + sA] = eA;
      wsCopy[row * LSRC + sB] = eB;
      atomicAdd(&rowAcc[li], eA + eB);
    }
  }
  __syncthreads();
  if (t < 32) atomicAdd(&rowSum[b * 128 + l0 + t], rowAcc[t]);
}

// ---- K4: main GEMM 1024x32000x512 bf16 MFMA, register-direct pipeline -------
// grid (8, 250): x = m-tile, y = n-tile. A prefetch dist 1, B prefetch dist 2;
// sched_barrier(0) pins loads above the MFMAs so the compiler can't sink them.
__global__ __launch_bounds__(256) void k_gemm(const u16* __restrict__ Ab,
                                              const u16* __restrict__ Wb,
                                              const float* __restrict__ bgen,
                                              u16* __restrict__ wsE,
                                              float* __restrict__ rowSum) {
  int t = threadIdx.x;
  int wid = t >> 6, lane = t & 63;
  int wm = wid >> 1, wn = wid & 1;         // 2x2 waves over 128x128 tile
  int quad = lane >> 4, l16 = lane & 15;
  const u16* Ag = Ab + (size_t)blockIdx.x * (16 * 4096)
                + (wm * 64 + l16) * 32 + quad * 8;
  const u16* Bg = Wb + (size_t)blockIdx.y * (16 * 4096)
                + (wn * 64 + l16) * 32 + quad * 8;
  floatx4 acc[4][4];
#pragma unroll
  for (int i = 0; i < 4; ++i)
#pragma unroll
    for (int j = 0; j < 4; ++j) acc[i][j] = (floatx4){0.f, 0.f, 0.f, 0.f};

  short8 aF[2][4], bF[3][4];
#pragma unroll
  for (int i = 0; i < 4; ++i) {            // prologue: A(0), B(0), B(1)
    aF[0][i] = *(const short8*)(Ag + i * 512);
    bF[0][i] = *(const short8*)(Bg + i * 512);
    bF[1][i] = *(const short8*)(Bg + 4096 + i * 512);
  }
#pragma unroll
  for (int kt = 0; kt < 16; ++kt) {
    if (kt < 15) {
      const u16* ap = Ag + (kt + 1) * 4096;
#pragma unroll
      for (int i = 0; i < 4; ++i) aF[(kt + 1) & 1][i] = *(const short8*)(ap + i * 512);
    }
    if (kt < 14) {
      const u16* bp = Bg + (kt + 2) * 4096;
#pragma unroll
      for (int i = 0; i < 4; ++i) bF[(kt + 2) % 3][i] = *(const short8*)(bp + i * 512);
    }
    __builtin_amdgcn_sched_barrier(0);     // keep the prefetch loads above MFMAs
#pragma unroll
    for (int mt = 0; mt < 4; ++mt)
#pragma unroll
      for (int nt = 0; nt < 4; ++nt)
        acc[mt][nt] = __builtin_amdgcn_mfma_f32_16x16x32_bf16(aF[kt & 1][mt],
                                                              bF[kt % 3][nt],
                                                              acc[mt][nt], 0, 0, 0);
  }

  // epilogue: e = exp((acc + b) * H^-0.5); store bf16; reduce row sums
  int row0 = blockIdx.x * 128 + wm * 64;
  int col0 = blockIdx.y * 128 + wn * 64;
  float bg[4];
#pragma unroll
  for (int nt = 0; nt < 4; ++nt) bg[nt] = bgen[col0 + nt * 16 + l16];
#pragma unroll
  for (int mt = 0; mt < 4; ++mt) {
    float rs[4] = {0.f, 0.f, 0.f, 0.f};
#pragma unroll
    for (int nt = 0; nt < 4; ++nt) {
      int col = col0 + nt * 16 + l16;
#pragma unroll
      for (int r = 0; r < 4; ++r) {
        int row = row0 + mt * 16 + quad * 4 + r;    // C/D layout (m89)
        float e = __expf((acc[mt][nt][r] + bg[nt]) * SCALEF);
        wsE[(size_t)row * NV + col] = f2bf(e);
        rs[r] += e;
      }
    }
#pragma unroll
    for (int r = 0; r < 4; ++r) {
      float v = rs[r];
      v += __shfl_xor(v, 1, 64);
      v += __shfl_xor(v, 2, 64);
      v += __shfl_xor(v, 4, 64);
      v += __shfl_xor(v, 8, 64);
      if (l16 == 0) atomicAdd(&rowSum[row0 + mt * 16 + quad * 4 + r], v);
    }
  }
}

// ---- K5: normalize + scatter (one block owns one output row) ----------------
__global__ __launch_bounds__(256) void k_norm(const u16* __restrict__ wsE,
                                              const float* __restrict__ wsCopy,
                                              const float* __restrict__ rowSum,
                                              const int* __restrict__ context,
                                              const int* __restrict__ tp,
                                              const int* __restrict__ action,
                                              const int* __restrict__ loc2glo,
                                              float* __restrict__ out) {
  int r = blockIdx.x, b = r >> 7;
  float inv = 1.0f / rowSum[r];
  const uint4* src = (const uint4*)(wsE + (size_t)r * NV);
  float4* dst = (float4*)(out + (size_t)r * NV);
  for (int c = threadIdx.x; c < NV / 8; c += 256) {
    uint4 v = src[c];
    float4 lo, hi;
    lo.x = __uint_as_float(v.x << 16) * inv;
    lo.y = __uint_as_float(v.x & 0xffff0000u) * inv;
    lo.z = __uint_as_float(v.y << 16) * inv;
    lo.w = __uint_as_float(v.y & 0xffff0000u) * inv;
    hi.x = __uint_as_float(v.z << 16) * inv;
    hi.y = __uint_as_float(v.z & 0xffff0000u) * inv;
    hi.z = __uint_as_float(v.w << 16) * inv;
    hi.w = __uint_as_float(v.w & 0xffff0000u) * inv;
    dst[2 * c] = lo;
    dst[2 * c + 1] = hi;
  }
  __syncthreads();   // drains stores (vmcnt) so atomics below see them at L2
  int t = threadIdx.x;
  float* op = out + (size_t)r * NV;
  atomicAdd(op + context[b * 256 + t], wsCopy[r * LSRC + t] * inv);
  if (t < 32) {
    atomicAdd(op + loc2glo[tp[b * 32 + t]],     wsCopy[r * LSRC + 256 + t] * inv);
    atomicAdd(op + loc2glo[action[b * 32 + t]], wsCopy[r * LSRC + 288 + t] * inv);
  }
}

// ---- launch -----------------------------------------------------------------
extern "C" void kernel_launch(void* const* d_in, const int* in_sizes, int n_in,
                              void* d_out, int out_size, void* d_ws, size_t ws_size,
                              hipStream_t stream) {
  const float* dec  = (const float*)d_in[0];
  const float* srch = (const float*)d_in[1];
  const float* Wg   = (const float*)d_in[2];
  const float* bg   = (const float*)d_in[3];
  const int*   mask = (const int*)d_in[4];
  const int*   ctx  = (const int*)d_in[5];
  const int*   tp   = (const int*)d_in[6];
  const int*   act  = (const int*)d_in[7];
  const int*   l2g  = (const int*)d_in[8];
  float* out = (float*)d_out;

  char* ws = (char*)d_ws;
  // ws layout (bytes):
  u16*   Wb      = (u16*)(ws);                    // 32,768,000  bf16 W tiled
  u16*   wsE     = (u16*)(ws + 32768000);         // 65,536,000  bf16 exp(gen)
  u16*   Ab      = (u16*)(ws + 98304000);         //  1,048,576  bf16 A tiled
  float* wsCopy  = (float*)(ws + 99352576);       //  1,310,720  fp32 exp(copy)
  float* rowSum  = (float*)(ws + 100663296);      //      4,096  fp32 row sums

  hipLaunchKernelGGL(k_convA, dim3(256), dim3(256), 0, stream, dec, Ab, rowSum);
  hipLaunchKernelGGL(k_convW, dim3(4000), dim3(256), 0, stream, Wg, Wb);
  hipLaunchKernelGGL(k_copy, dim3(1280), dim3(256), 0, stream, dec, srch, mask, wsCopy, rowSum);
  hipLaunchKernelGGL(k_gemm, dim3(8, 250), dim3(256), 0, stream, Ab, Wb, bg, wsE, rowSum);
  hipLaunchKernelGGL(k_norm, dim3(MROWS), dim3(256), 0, stream, wsE, wsCopy, rowSum,
                     ctx, tp, act, l2g, out);
}